// Round 6
// baseline (87.466 us; speedup 1.0000x reference)
//
#include <hip/hip_runtime.h>

// AugmentShallow, round 6: round-4 structure (gather t, GEMM after mean —
// proven 9.77e-4 absmax) + two fixes:
//   1. k_out2 out-stores are NONTEMPORAL -> the 64MiB out stream no longer
//      evicts the 2MiB/XCD t slice from L2; gather stays L2-resident.
//   2. Weights pre-split ONCE (k_prep) into f16 hi/lo planes in ws
//      (bit-identical values to the old in-register splitW8) -> kills
//      ~320 redundant VALU insts per pass per wave and ~30 VGPRs.
//
// Pipeline: k_prep (split planes) ; k_mlp (t[b,j] = MLP(x[b,j]), f16) ;
//           k_out2 (m = mean_12 gather(t) -> LDS -> out = W2 m + b2).
//
// ws: [0,16Mi) t f16 [65536][128]; [16Mi, +256Ki) split weight planes.

typedef __attribute__((ext_vector_type(8))) _Float16 h8;
typedef __attribute__((ext_vector_type(4))) _Float16 h4;
typedef __attribute__((ext_vector_type(4))) float    f4;

#define MFMA_H __builtin_amdgcn_mfma_f32_16x16x32_f16

#define LO_SCALE_INV 2.44140625e-4f   // 2^-12

// plane offsets in f16 elements within the planes region
#define WC0H 0
#define WC0L 16384
#define WC1H 32768
#define WC1L 49152
#define W2H  65536
#define W2L  98304

// ---------------------------------------------------------------------------
// Prep: split Wc0/Wc1/W2 (fp32) into f16 hi/lo planes.
// hi = (f16)v ; lo = (f16)((v - hi) * 4096)  -- identical to round-4 splitW8.
// ---------------------------------------------------------------------------
__global__ void k_prep(const float* __restrict__ Wc0, const float* __restrict__ Wc1,
                       const float* __restrict__ W2, _Float16* __restrict__ planes)
{
    const int i = blockIdx.x * 256 + threadIdx.x;   // 0..65535
    float v; _Float16 *ph, *pl;
    if (i < 16384) {
        v = Wc0[i]; ph = planes + WC0H + i; pl = planes + WC0L + i;
    } else if (i < 32768) {
        const int j = i - 16384;
        v = Wc1[j]; ph = planes + WC1H + j; pl = planes + WC1L + j;
    } else {
        const int j = i - 32768;
        v = W2[j];  ph = planes + W2H + j;  pl = planes + W2L + j;
    }
    const _Float16 h = (_Float16)v;
    *ph = h;
    *pl = (_Float16)((v - (float)h) * 4096.f);
}

// One 32-oc x 64-pt GEMM pass on MFMA, weights from pre-split planes.
// wh/wl point at the 32-oc strip base (ocb*128). bias may be nullptr.
template <class F>
__device__ __forceinline__ void pass32p(
    const _Float16* __restrict__ hin,     // LDS [64][128], chunk^p7 swizzle
    const _Float16* __restrict__ wh,
    const _Float16* __restrict__ wl,
    const float* __restrict__ bias,
    int fr, int g, F&& emit)
{
    h8 Ah[2][4], Al[2][4];
#pragma unroll
    for (int T = 0; T < 2; ++T)
#pragma unroll
        for (int c = 0; c < 4; ++c) {
            const long off = (long)(T * 16 + fr) * 128 + c * 32 + g * 8;
            Ah[T][c] = *(const h8*)(wh + off);
            Al[T][c] = *(const h8*)(wl + off);
        }

    f4 bv[2] = {{0.f, 0.f, 0.f, 0.f}, {0.f, 0.f, 0.f, 0.f}};
    if (bias) {
#pragma unroll
        for (int T = 0; T < 2; ++T) {
            const float4 q = *(const float4*)(bias + T * 16 + g * 4);
            bv[T] = (f4){q.x, q.y, q.z, q.w};
        }
    }

#pragma unroll
    for (int p = 0; p < 4; ++p) {
        const int pt = p * 16 + fr;
        const int p7 = pt & 7;
        h8 B[4];
#pragma unroll
        for (int c = 0; c < 4; ++c)
            B[c] = *(const h8*)&hin[pt * 128 + (((4 * c + g) ^ p7) << 3)];

        f4 ahi[2] = {bv[0], bv[1]};
        f4 alo[2] = {{0.f, 0.f, 0.f, 0.f}, {0.f, 0.f, 0.f, 0.f}};
#pragma unroll
        for (int c = 0; c < 4; ++c)
#pragma unroll
            for (int T = 0; T < 2; ++T) {
                ahi[T] = MFMA_H(Ah[T][c], B[c], ahi[T], 0, 0, 0);
                alo[T] = MFMA_H(Al[T][c], B[c], alo[T], 0, 0, 0);
            }
        f4 rv[2];
#pragma unroll
        for (int T = 0; T < 2; ++T)
#pragma unroll
            for (int j = 0; j < 4; ++j)
                rv[T][j] = fmaf(alo[T][j], LO_SCALE_INV, ahi[T][j]);
        emit(p, rv);
    }
}

// ---------------------------------------------------------------------------
// Kernel 1: point MLP. 1024 blocks x 256 thr, 64 points per block.
// Wave w owns oc strip [32w, 32w+32); weights from planes (L2-hit h8 loads).
// h1 -> hA, h2 -> hB, h3 -> t (global f16).
// ---------------------------------------------------------------------------
__global__ __launch_bounds__(256) void k_mlp(
    const float* __restrict__ x,
    const float* __restrict__ W1, const float* __restrict__ b1,
    const float* __restrict__ bc0, const float* __restrict__ bc1,
    const _Float16* __restrict__ planes,
    _Float16* __restrict__ t)
{
    __shared__ __align__(16) _Float16 hA[64 * 128];   // 16 KiB
    __shared__ __align__(16) _Float16 hB[64 * 128];   // 16 KiB

    const int tid = threadIdx.x;
    const int bid = blockIdx.x;
    const int lb  = (bid & 7) * 128 + (bid >> 3);   // batch = lb>>7 = bid&7 (XCD pin)
    const long pblk = (long)lb * 64;

    // ---- layer 1 (VALU, K=3, no relu): thread = (pt, 32-ch quarter) ----
    {
        const int pt  = tid >> 2;
        const int q4  = tid & 3;
        const int ch0 = q4 * 32;
        const float* xp = x + (pblk + pt) * 3;
        const float x0 = xp[0], x1 = xp[1], x2 = xp[2];
        const int p7 = pt & 7;
#pragma unroll
        for (int q = 0; q < 4; ++q) {
            h8 hv;
#pragma unroll
            for (int j = 0; j < 8; ++j) {
                const int c = ch0 + q * 8 + j;
                float v = b1[c];
                v = fmaf(W1[c * 3 + 0], x0, v);
                v = fmaf(W1[c * 3 + 1], x1, v);
                v = fmaf(W1[c * 3 + 2], x2, v);
                hv[j] = (_Float16)v;
            }
            const int chunk = q4 * 4 + q;
            *(h8*)&hA[pt * 128 + ((chunk ^ p7) << 3)] = hv;
        }
    }
    __syncthreads();

    const int lane = tid & 63;
    const int w  = tid >> 6;
    const int fr = lane & 15;
    const int g  = lane >> 4;
    const int ocb = w * 32;
    const long strip = (long)ocb * 128;

    // mid-layer store: relu + f16 + swizzled LDS column-strip write
    auto storeMid = [&](_Float16* hout, int p, f4* rv) {
        const int pt = p * 16 + fr;
        const int p7 = pt & 7;
#pragma unroll
        for (int T = 0; T < 2; ++T) {
            const int ocoff = ocb + T * 16 + g * 4;
            h4 o;
#pragma unroll
            for (int r = 0; r < 4; ++r) o[r] = (_Float16)fmaxf(rv[T][r], 0.f);
            const int sidx = pt * 128 + (((ocoff >> 3) ^ p7) << 3) + (ocoff & 7);
            *(h4*)&hout[sidx] = o;
        }
    };

    // ---- layer 2: hB = relu(Wc0 hA + bc0) ----
    pass32p(hA, planes + WC0H + strip, planes + WC0L + strip, bc0 + ocb, fr, g,
            [&](int p, f4* rv) { storeMid(hB, p, rv); });
    __syncthreads();

    // ---- layer 3: hA?? no -> t = relu(Wc1 hB + bc1), direct to global ----
    pass32p(hB, planes + WC1H + strip, planes + WC1L + strip, bc1 + ocb, fr, g,
            [&](int p, f4* rv) {
                const int ptl = p * 16 + fr;
                const long pt = pblk + ptl;
#pragma unroll
                for (int T = 0; T < 2; ++T) {
                    const int ocoff = ocb + T * 16 + g * 4;
                    h4 o;
#pragma unroll
                    for (int r = 0; r < 4; ++r)
                        o[r] = (_Float16)fmaxf(rv[T][r], 0.f);
                    *(h4*)&t[pt * 128 + ocoff] = o;
                }
            });
}

// ---------------------------------------------------------------------------
// Kernel 2: gather-mean -> LDS -> out = W2 m + b2, NT out stores.
// 1024 blocks x 256 thr; block = 64 pts of one batch (bid&7 -> XCD pin).
// W2 half-0 fragments loaded BEFORE the gather (latency hidden under it).
// ---------------------------------------------------------------------------
__global__ __launch_bounds__(256) void k_out2(
    const int* __restrict__ knn,
    const _Float16* __restrict__ t,
    const _Float16* __restrict__ planes,
    const float* __restrict__ b2,
    float* __restrict__ out)
{
    __shared__ __align__(16) _Float16 mS[64 * 128];   // 16 KiB

    const int tid = threadIdx.x;
    const int bid = blockIdx.x;
    const int lb  = (bid & 7) * 128 + (bid >> 3);   // batch = lb>>7 = bid&7
    const long pbase = (long)lb * 64;
    const long bbase = (pbase >> 13) << 13;         // batch row base in t

    const int lane = tid & 63;
    const int w  = tid >> 6;
    const int fr = lane & 15;
    const int g  = lane >> 4;

    auto loadW = [&](int ocb, h8 (&Ah)[2][4], h8 (&Al)[2][4]) {
#pragma unroll
        for (int T = 0; T < 2; ++T)
#pragma unroll
            for (int c = 0; c < 4; ++c) {
                const long off = (long)(ocb + T * 16 + fr) * 128 + c * 32 + g * 8;
                Ah[T][c] = *(const h8*)(planes + W2H + off);
                Al[T][c] = *(const h8*)(planes + W2L + off);
            }
    };

    // issue W2 half-0 loads first; latency hides under the gather
    h8 Ah[2][4], Al[2][4];
    loadW(0 + w * 32, Ah, Al);

    // ---- gather-mean into LDS: 2 passes x 32 pts; thread=(pt, 8-ch oct) ----
    {
        const int oct = tid & 7;
        const int o8  = oct * 8;
#pragma unroll 1
        for (int pass = 0; pass < 2; ++pass) {
            const int ptl = pass * 32 + (tid >> 3);
            const int* ip = knn + (pbase + ptl) * 12;
            int idx[12];
            *(int4*)&idx[0] = *(const int4*)(ip + 0);
            *(int4*)&idx[4] = *(const int4*)(ip + 4);
            *(int4*)&idx[8] = *(const int4*)(ip + 8);

            float acc[16];
#pragma unroll
            for (int c = 0; c < 16; ++c) acc[c] = 0.f;
#pragma unroll 4
            for (int k = 0; k < 12; ++k) {
                const _Float16* tp = t + (bbase + idx[k]) * 128;
                const h8 va = *(const h8*)(tp + o8);
                const h8 vb = *(const h8*)(tp + 64 + o8);
#pragma unroll
                for (int j = 0; j < 8; ++j) acc[j] += (float)va[j];
#pragma unroll
                for (int j = 0; j < 8; ++j) acc[8 + j] += (float)vb[j];
            }
            h8 oa, ob;
#pragma unroll
            for (int j = 0; j < 8; ++j) {
                oa[j] = (_Float16)(acc[j] * (1.f / 12.f));
                ob[j] = (_Float16)(acc[8 + j] * (1.f / 12.f));
            }
            const int p7 = ptl & 7;
            *(h8*)&mS[ptl * 128 + ((oct ^ p7) << 3)]       = oa;
            *(h8*)&mS[ptl * 128 + (((oct + 8) ^ p7) << 3)] = ob;
        }
    }
    __syncthreads();

    // ---- GEMM: out = W2 m + b2, two 128-oc halves, NT stores ----
#pragma unroll 1
    for (int half = 0; half < 2; ++half) {
        const int ocb = half * 128 + w * 32;
        if (half) loadW(ocb, Ah, Al);

        f4 bv[2];
#pragma unroll
        for (int T = 0; T < 2; ++T) {
            const float4 q = *(const float4*)(b2 + ocb + T * 16 + g * 4);
            bv[T] = (f4){q.x, q.y, q.z, q.w};
        }

#pragma unroll
        for (int p = 0; p < 4; ++p) {
            const int ptl = p * 16 + fr;
            const int p7  = ptl & 7;
            h8 B[4];
#pragma unroll
            for (int c = 0; c < 4; ++c)
                B[c] = *(const h8*)&mS[ptl * 128 + (((4 * c + g) ^ p7) << 3)];

            f4 ahi[2] = {bv[0], bv[1]};
            f4 alo[2] = {{0.f, 0.f, 0.f, 0.f}, {0.f, 0.f, 0.f, 0.f}};
#pragma unroll
            for (int c = 0; c < 4; ++c)
#pragma unroll
                for (int T = 0; T < 2; ++T) {
                    ahi[T] = MFMA_H(Ah[T][c], B[c], ahi[T], 0, 0, 0);
                    alo[T] = MFMA_H(Al[T][c], B[c], alo[T], 0, 0, 0);
                }
#pragma unroll
            for (int T = 0; T < 2; ++T) {
                f4 o;
#pragma unroll
                for (int j = 0; j < 4; ++j)
                    o[j] = fmaf(alo[T][j], LO_SCALE_INV, ahi[T][j]);
                float* op = out + (pbase + ptl) * 256 + ocb + T * 16 + g * 4;
                __builtin_nontemporal_store(o, (f4*)op);
            }
        }
    }
}

// ---------------------------------------------------------------------------

extern "C" void kernel_launch(void* const* d_in, const int* in_sizes, int n_in,
                              void* d_out, int out_size, void* d_ws, size_t ws_size,
                              hipStream_t stream)
{
    const float* x   = (const float*)d_in[0];
    const int*   knn = (const int*)d_in[1];
    const float* W1  = (const float*)d_in[2];
    const float* b1  = (const float*)d_in[3];
    const float* Wc0 = (const float*)d_in[4];
    const float* bc0 = (const float*)d_in[5];
    const float* Wc1 = (const float*)d_in[6];
    const float* bc1 = (const float*)d_in[7];
    const float* W2  = (const float*)d_in[8];
    const float* b2  = (const float*)d_in[9];
    float* out = (float*)d_out;

    _Float16* t      = (_Float16*)d_ws;                                      // 16 MiB
    _Float16* planes = (_Float16*)((char*)d_ws + (size_t)16 * 1024 * 1024);  // 256 KiB

    k_prep<<<dim3(256),  dim3(256), 0, stream>>>(Wc0, Wc1, W2, planes);
    k_mlp <<<dim3(1024), dim3(256), 0, stream>>>(x, W1, b1, bc0, bc1, planes, t);
    k_out2<<<dim3(1024), dim3(256), 0, stream>>>(knn, t, planes, b2, out);
}